// Round 5
// baseline (2337.899 us; speedup 1.0000x reference)
//
#include <hip/hip_runtime.h>
#include <hip/hip_bf16.h>
#include <math.h>

// Problem constants (fixed by reference: x,y are (4096, 512) fp32)
#define N 4096
#define D 512
#define SINK_PASSES 100           // 50 iterations x (f-update, g-update)

// log-domain constants (base-2 internally; v_exp_f32/v_log_f32 are base-2)
#define K_LOG2 14.426950408889634f          // (1/eps) * log2(e), eps = 0.1
#define INV_K  0.06931471805599453f         // 1/K_LOG2 = eps*ln2
#define TWO_K  28.853900817779268f          // 2 * K_LOG2
#define NEG_EPS_LN2 (-0.06931471805599453f) // -eps * ln(2)
#define EPS_NEG_LOGMU 0.8317766166719343f   // -eps * log_mu = eps * log(4096)

// Sparse-candidate machinery: entries with u < rowmax - MARGIN (log2 units)
// contribute < 2^-(MARGIN - drift) each; drift measured ~60 log2 units.
#define CAP 512
#define MARGIN 200.0f
// Sentinel candidate word: j=0, S=-inf (fp16 0xFC00) -> u=-inf -> contributes 0.
#define SENTINEL 0x0000FC00u
// Register-cached slots per row (pass-invariant a_j = 2K*S_j - othK[j] live in
// VGPRs; slots [0,RC) never touch memory in the pass loop). Multiple of 8.
#define RC 16
// Batch-loop cap; rows with cnt > MAINCAP get wave-cooperative cleanup.
#define MAINCAP 64

typedef __bf16   bf16x8 __attribute__((ext_vector_type(8)));
typedef _Float16 halfx8 __attribute__((ext_vector_type(8)));
typedef float    floatx4 __attribute__((ext_vector_type(4)));
typedef unsigned short ushortx8v __attribute__((ext_vector_type(8)));

// ---------- convert fp32 -> bf16 (GEMM inputs) ----------
__global__ void cvt_bf16_kernel(const float* __restrict__ in, __bf16* __restrict__ out, int count) {
    int idx = blockIdx.x * blockDim.x + threadIdx.x;
    if (idx < count) out[idx] = (__bf16)in[idx];
}

// ---------- row squared norms (fp32 inputs, exact) ----------
__global__ void sqnorm_kernel(const float* __restrict__ in, float* __restrict__ out) {
    int row = blockIdx.x;
    const float* p = in + (size_t)row * D;
    float s = 0.f;
    for (int k = threadIdx.x; k < D; k += 64) { float v = p[k]; s += v * v; }
    for (int off = 32; off > 0; off >>= 1) s += __shfl_down(s, off);
    if (threadIdx.x == 0) out[row] = s;
}

// ---------- 128x128-tile GEMM: out = A @ B^T (fp16), writes tile + transposed tile ----------
__global__ __launch_bounds__(256) void gemm128_kernel(
    const __bf16* __restrict__ A, const __bf16* __restrict__ Bm,
    _Float16* __restrict__ out1, _Float16* __restrict__ out2, int sym) {
    if (sym && blockIdx.x > blockIdx.y) return;
    __shared__ char smem[34816];
    __bf16* ldsA = (__bf16*)smem;           // [128][64] swizzled
    __bf16* ldsB = ldsA + 128 * 64;

    int t = threadIdx.x;
    int w = t >> 6, lane = t & 63;
    int m = lane & 15, q = lane >> 4;
    int wr = w & 1, wc = w >> 1;
    int m0 = blockIdx.x * 128, n0 = blockIdx.y * 128;

    int srow = t >> 1, shalf = t & 1;
    const bf16x8* gA = (const bf16x8*)(A  + (size_t)(m0 + srow) * D + shalf * 32);
    const bf16x8* gB = (const bf16x8*)(Bm + (size_t)(n0 + srow) * D + shalf * 32);

    floatx4 acc[4][4];
#pragma unroll
    for (int i = 0; i < 4; i++)
#pragma unroll
        for (int j = 0; j < 4; j++) acc[i][j] = (floatx4){0.f, 0.f, 0.f, 0.f};

    for (int slab = 0; slab < 8; slab++) {
        bf16x8 va[4], vb[4];
#pragma unroll
        for (int i = 0; i < 4; i++) {
            va[i] = gA[slab * 8 + i];
            vb[i] = gB[slab * 8 + i];
        }
        __syncthreads();
#pragma unroll
        for (int i = 0; i < 4; i++) {
            int cp = (shalf * 4 + i) ^ (srow & 7);
            *(bf16x8*)(ldsA + srow * 64 + cp * 8) = va[i];
            *(bf16x8*)(ldsB + srow * 64 + cp * 8) = vb[i];
        }
        __syncthreads();
#pragma unroll
        for (int kk = 0; kk < 2; kk++) {
            bf16x8 af[4], bfr[4];
#pragma unroll
            for (int mt = 0; mt < 4; mt++) {
                int cp = (kk * 4 + q) ^ (m & 7);
                af[mt]  = *(const bf16x8*)(ldsA + (wr * 64 + mt * 16 + m) * 64 + cp * 8);
                bfr[mt] = *(const bf16x8*)(ldsB + (wc * 64 + mt * 16 + m) * 64 + cp * 8);
            }
#pragma unroll
            for (int mt = 0; mt < 4; mt++)
#pragma unroll
                for (int nt = 0; nt < 4; nt++)
                    acc[mt][nt] = __builtin_amdgcn_mfma_f32_16x16x32_bf16(
                        af[mt], bfr[nt], acc[mt][nt], 0, 0, 0);
        }
    }

    __syncthreads();
    _Float16* et = (_Float16*)smem + w * (64 * 66);
#pragma unroll
    for (int mt = 0; mt < 4; mt++)
#pragma unroll
        for (int nt = 0; nt < 4; nt++)
#pragma unroll
            for (int r = 0; r < 4; r++)
                et[(mt * 16 + q * 4 + r) * 66 + nt * 16 + m] = (_Float16)acc[mt][nt][r];

    int l3 = lane >> 3, c8 = lane & 7;
#pragma unroll
    for (int rr = 0; rr < 8; rr++) {
        int rl = rr * 8 + l3;
        halfx8 v = *(const halfx8*)(et + rl * 66 + c8 * 8);
        *(halfx8*)(out1 + (size_t)(m0 + wr * 64 + rl) * N + n0 + wc * 64 + c8 * 8) = v;
    }
#pragma unroll
    for (int rr = 0; rr < 8; rr++) {
        int rT = rr * 8 + l3;
        halfx8 v;
#pragma unroll
        for (int k = 0; k < 8; k++) v[k] = et[(c8 * 8 + k) * 66 + rT];
        *(halfx8*)(out2 + (size_t)(n0 + wc * 64 + rT) * N + m0 + wr * 64 + c8 * 8) = v;
    }
}

// ---------- full Sinkhorn pass (3 pairs, 1 row/wave, 3072 blocks) ----------
// BUILD=1: collect candidates u >= prevmax - MARGIN via ballot compaction into
// the TRANSPOSED layout candT[set][slot][row] (addr = (set*CAP+slot)*N + row),
// then SENTINEL-pad each list to a multiple of 8.
template<int BUILD>
__global__ __launch_bounds__(256) void lse_full3_kernel(
    const _Float16* __restrict__ Sxy, const _Float16* __restrict__ STxy,
    const _Float16* __restrict__ Sxx, const _Float16* __restrict__ Syy,
    const float* __restrict__ x2, const float* __restrict__ y2,
    float* __restrict__ Pxy0, float* __restrict__ Pxy1,
    float* __restrict__ Pxx0, float* __restrict__ Pxx1,
    float* __restrict__ Pyy0, float* __restrict__ Pyy1,
    int odd,
    unsigned int* __restrict__ cand, int* __restrict__ cnt,
    float* __restrict__ prevmax) {
    __shared__ float gykT[8 * 512];
    int pair = blockIdx.x >> 10;
    int blk = blockIdx.x & 1023;
    const _Float16* M;
    const float *own, *other, *pin;
    float* pout;
    if (pair == 0) {
        if (odd) { M = Sxy;  own = x2; other = y2; pin = Pxy0; pout = Pxy1; }
        else     { M = STxy; own = y2; other = x2; pin = Pxy1; pout = Pxy0; }
    } else if (pair == 1) {
        M = Sxx; own = x2; other = x2;
        if (odd) { pin = Pxx0; pout = Pxx1; } else { pin = Pxx1; pout = Pxx0; }
    } else {
        M = Syy; own = y2; other = y2;
        if (odd) { pin = Pyy0; pout = Pyy1; } else { pin = Pyy1; pout = Pyy0; }
    }

    int wave = threadIdx.x >> 6, lane = threadIdx.x & 63;

    {   // stage gykT[(j&7)*512 + (j>>3)] = (pin[j] - other[j]) * K
        const floatx4* pi4 = (const floatx4*)pin;
        const floatx4* so4 = (const floatx4*)other;
        for (int tt = threadIdx.x; tt < N / 4; tt += 256) {
            floatx4 p = pi4[tt], o = so4[tt];
            int j = tt * 4;
#pragma unroll
            for (int k2 = 0; k2 < 4; k2++) {
                int jj = j + k2;
                gykT[(jj & 7) * 512 + (jj >> 3)] = (p[k2] - o[k2]) * K_LOG2;
            }
        }
    }
    __syncthreads();

    int row = blk * 4 + wave;
    int set = pair * 2 + (odd ? 0 : 1);
    int idx = set * N + row;
    float thr = 0.f;
    size_t cbase = 0;
    int ncand = 0;
    unsigned long long lt_mask = (1ull << lane) - 1ull;
    if (BUILD) { thr = prevmax[idx] - MARGIN; cbase = (size_t)set * CAP * N + row; }

    const halfx8* srow = (const halfx8*)(M + (size_t)row * N);
    float m = -INFINITY, s = 0.f;
#pragma unroll
    for (int c = 0; c < 8; c++) {
        int chunk = c * 64 + lane;
        halfx8 sv = srow[chunk];
        int j0 = chunk * 8;
        float u[8];
#pragma unroll
        for (int k = 0; k < 8; k++)
            u[k] = fmaf((float)sv[k], TWO_K, gykT[k * 512 + chunk]);
        float mloc = fmaxf(fmaxf(fmaxf(u[0], u[1]), fmaxf(u[2], u[3])),
                           fmaxf(fmaxf(u[4], u[5]), fmaxf(u[6], u[7])));
        if (BUILD) {
            if (__ballot(mloc >= thr)) {
                ushortx8v sb = __builtin_bit_cast(ushortx8v, sv);
#pragma unroll
                for (int k = 0; k < 8; k++) {
                    bool hit = (u[k] >= thr);
                    unsigned long long mask = __ballot(hit);
                    if (hit) {
                        int slot = ncand + __popcll(mask & lt_mask);
                        if (slot < CAP)
                            cand[cbase + (size_t)slot * N] = ((unsigned int)(j0 + k) << 16) | (unsigned int)sb[k];
                    }
                    ncand += (int)__popcll(mask);
                }
            }
        }
        float M2 = fmaxf(m, mloc);
        float acc = 0.f;
#pragma unroll
        for (int k = 0; k < 8; k++) acc += exp2f(u[k] - M2);
        s = s * exp2f(m - M2) + acc;
        m = M2;
    }
    if (BUILD) {
        // sentinel-pad to a multiple of 8 (ncand is identical on all lanes)
        int padded = (ncand + 7) & ~7;
        if (padded > CAP) padded = CAP;
        for (int sl = ncand + lane; sl < padded; sl += 64)
            cand[cbase + (size_t)sl * N] = SENTINEL;
    }
    for (int off = 32; off > 0; off >>= 1) {
        float m2 = __shfl_down(m, off), s2 = __shfl_down(s, off);
        float Mx = fmaxf(m, m2);
        s = s * exp2f(m - Mx) + s2 * exp2f(m2 - Mx);
        m = Mx;
    }
    if (lane == 0) {
        float xk = own[row] * K_LOG2;
        pout[row] = NEG_EPS_LN2 * (m + __log2f(s) - xk) + EPS_NEG_LOGMU;
        prevmax[idx] = m;
        if (BUILD) cnt[idx] = ncand;
    }
}

// ---------- register-cached sparse pass body ----------
// Slots [0,RC) of every row live in VGPRs as (a_j, j): u = a_j + PK[j], so the
// steady-state pass is pure {LDS-gather, add, exp2, add} -- zero global memory.
// Invalid/sentinel slots carry a_j = -inf -> contribute 0. All indices are
// compile-time (rule #20) so the arrays stay in registers.
__device__ __forceinline__ void regpass16(
    const float (&aA)[4][RC], const unsigned (&jp)[4][RC / 2],
    const float (&mf)[4], const float* __restrict__ pinK,
    float (&s4)[4], float (&mt4)[4]) {
#pragma unroll
    for (int i = 0; i < 4; i++) { s4[i] = 0.f; mt4[i] = -INFINITY; }
#pragma unroll
    for (int c = 0; c < RC; c++) {
#pragma unroll
        for (int i = 0; i < 4; i++) {
            int j = (int)((jp[i][c >> 1] >> ((c & 1) * 16)) & 0xffffu);
            float u = aA[i][c] + pinK[j];
            mt4[i] = fmaxf(mt4[i], u);
            s4[i] += exp2f(u - mf[i]);
        }
    }
}

// ---------- persistent sparse phase: ONE block per pair, all state in LDS ----------
// 3 blocks x 1024 threads, plain launch. Potentials live in LDS pre-scaled by
// K_LOG2; one __syncthreads per pass. Candidate slots [0,RC) are hoisted into
// registers at launch (a_j = 2K*S_j - othK[j] is PASS-INVARIANT; only PK[j]
// changes). Remainder slots [RC, MAINCAP) use the batch-8 prefetched global
// loop; cnt > MAINCAP gets wave-cooperative cleanup; cnt==0/cnt>CAP dense
// fallback. logsumexp uses the build-time row max (prevmax) as a FIXED
// normalizer (defer-max); true max tracked to refresh prevmax for re-BUILD.
__global__ __launch_bounds__(1024) void sink_sparse3_kernel(
    const _Float16* __restrict__ Sxy, const _Float16* __restrict__ STxy,
    const _Float16* __restrict__ Sxx, const _Float16* __restrict__ Syy,
    const float* __restrict__ x2, const float* __restrict__ y2,
    float* __restrict__ Pxy0, float* __restrict__ Pxy1,
    float* __restrict__ Pxx0, float* __restrict__ Pxx1,
    float* __restrict__ Pyy0, float* __restrict__ Pyy1,
    const unsigned int* __restrict__ candT, const int* __restrict__ cnt,
    float* __restrict__ prevmax, int p_start, int p_end, int write_odd) {
    __shared__ float PKev[N];    // even-set potentials * K (read by odd passes)
    __shared__ float PKod[N];    // odd-set potentials * K
    __shared__ float othKO[N];   // other*K for odd passes
    __shared__ float othKE[N];   // other*K for even passes

    int pair = blockIdx.x;
    int tid = threadIdx.x;
    int lane = tid & 63;

    const _Float16 *MO, *ME;            // dense-fallback matrices, odd/even
    const float *ownO, *ownE, *othO, *othE;
    float *gPev, *gPod;                 // global ping-pong buffers
    if (pair == 0) {
        MO = Sxy;  ME = STxy; ownO = x2; othO = y2; ownE = y2; othE = x2;
        gPev = Pxy0; gPod = Pxy1;
    } else if (pair == 1) {
        MO = Sxx; ME = Sxx; ownO = x2; othO = x2; ownE = x2; othE = x2;
        gPev = Pxx0; gPod = Pxx1;
    } else {
        MO = Syy; ME = Syy; ownO = y2; othO = y2; ownE = y2; othE = y2;
        gPev = Pyy0; gPod = Pyy1;
    }
    int set0 = pair * 2;        // odd passes
    int set1 = pair * 2 + 1;    // even passes

    {   // init LDS: scaled even-buffer + fixed othK tables (vec4 per thread)
        floatx4 g = ((const floatx4*)gPev)[tid];
        floatx4 oo = ((const floatx4*)othO)[tid];
        floatx4 oe = ((const floatx4*)othE)[tid];
        floatx4 gs, os, es;
#pragma unroll
        for (int k = 0; k < 4; k++) {
            gs[k] = g[k] * K_LOG2;
            os[k] = oo[k] * K_LOG2;
            es[k] = oe[k] * K_LOG2;
        }
        *(floatx4*)(PKev + tid * 4) = gs;
        *(floatx4*)(othKO + tid * 4) = os;
        *(floatx4*)(othKE + tid * 4) = es;
    }

    // per-lane per-row state (4 rows, 2 parities)
    int   c0[4], c1[4];                  // raw counts
    int   cm0[4], cm1[4];                // batch-loop bounds in [RC, MAINCAP]
    float mf0[4], mf1[4], xk0[4], xk1[4];
    float lastm0[4], lastm1[4];
    bool  dense0[4], dense1[4], hv0[4], hv1[4];
#pragma unroll
    for (int i = 0; i < 4; i++) {
        int r = tid + 1024 * i;
        int cc0 = cnt[set0 * N + r], cc1 = cnt[set1 * N + r];
        c0[i] = cc0; c1[i] = cc1;
        dense0[i] = (cc0 < 1 || cc0 > CAP);
        dense1[i] = (cc1 < 1 || cc1 > CAP);
        hv0[i] = !dense0[i] && cc0 > MAINCAP;
        hv1[i] = !dense1[i] && cc1 > MAINCAP;
        int p0 = (cc0 + 7) & ~7;
        if (p0 < RC) p0 = RC; if (p0 > MAINCAP) p0 = MAINCAP;
        int p1 = (cc1 + 7) & ~7;
        if (p1 < RC) p1 = RC; if (p1 > MAINCAP) p1 = MAINCAP;
        cm0[i] = dense0[i] ? RC : p0;
        cm1[i] = dense1[i] ? RC : p1;
        mf0[i] = prevmax[set0 * N + r];
        mf1[i] = prevmax[set1 * N + r];
        lastm0[i] = mf0[i]; lastm1[i] = mf1[i];
        xk0[i] = ownO[r] * K_LOG2;
        xk1[i] = ownE[r] * K_LOG2;
    }
    // wave-uniform batch-loop bounds per parity
    int lcm0 = RC, lcm1 = RC;
#pragma unroll
    for (int i = 0; i < 4; i++) {
        lcm0 = cm0[i] > lcm0 ? cm0[i] : lcm0;
        lcm1 = cm1[i] > lcm1 ? cm1[i] : lcm1;
    }
    for (int off = 32; off > 0; off >>= 1) {
        int a = __shfl_xor(lcm0, off); lcm0 = a > lcm0 ? a : lcm0;
        int b = __shfl_xor(lcm1, off); lcm1 = b > lcm1 ? b : lcm1;
    }
    __syncthreads();   // LDS init complete (othK needed below)

    // ---- hoist candidate slots [0,RC) into registers (one-time) ----
    float aA0[4][RC], aA1[4][RC];
    unsigned jp0[4][RC / 2], jp1[4][RC / 2];
    {
        const unsigned int* cb0 = candT + (size_t)set0 * CAP * N + tid;
        const unsigned int* cb1 = candT + (size_t)set1 * CAP * N + tid;
#pragma unroll
        for (int i = 0; i < 4; i++) {
#pragma unroll
            for (int c = 0; c < RC; c++) {
                unsigned v0 = cb0[(size_t)c * N + i * 1024];
                unsigned v1 = cb1[(size_t)c * N + i * 1024];
                int j0 = (int)((v0 >> 16) & 4095u);
                int j1 = (int)((v1 >> 16) & 4095u);
                float S0 = (float)__builtin_bit_cast(_Float16, (unsigned short)(v0 & 0xffffu));
                float S1 = (float)__builtin_bit_cast(_Float16, (unsigned short)(v1 & 0xffffu));
                bool ok0 = (c < c0[i]) && !dense0[i];
                bool ok1 = (c < c1[i]) && !dense1[i];
                aA0[i][c] = ok0 ? fmaf(S0, TWO_K, -othKO[j0]) : -INFINITY;
                aA1[i][c] = ok1 ? fmaf(S1, TWO_K, -othKE[j1]) : -INFINITY;
                unsigned w0 = ok0 ? (unsigned)j0 : 0u;
                unsigned w1 = ok1 ? (unsigned)j1 : 0u;
                if ((c & 1) == 0) { jp0[i][c >> 1] = w0; jp1[i][c >> 1] = w1; }
                else              { jp0[i][c >> 1] |= w0 << 16; jp1[i][c >> 1] |= w1 << 16; }
            }
        }
    }

    for (int p = p_start; p <= p_end; ++p) {
        int odd = p & 1;
        float* pinK  = odd ? PKev : PKod;
        float* poutK = odd ? PKod : PKev;

        // ---- register-cached slots [0,RC): no memory traffic ----
        float s[4], mt[4];
        if (odd) regpass16(aA0, jp0, mf0, pinK, s, mt);
        else     regpass16(aA1, jp1, mf1, pinK, s, mt);

        // per-parity row state (constant-indexed selects -> stays in regs)
        int ccR[4], cmc[4]; float mfc[4], xkc[4]; bool dns[4], hvy[4];
#pragma unroll
        for (int i = 0; i < 4; i++) {
            ccR[i] = odd ? c0[i] : c1[i];
            cmc[i] = odd ? cm0[i] : cm1[i];
            mfc[i] = odd ? mf0[i] : mf1[i];
            xkc[i] = odd ? xk0[i] : xk1[i];
            dns[i] = odd ? dense0[i] : dense1[i];
            hvy[i] = odd ? hv0[i] : hv1[i];
        }
        int lcm = odd ? lcm0 : lcm1;
        size_t setbase = (size_t)(odd ? set0 : set1) * CAP * N;
        float* oK = odd ? othKO : othKE;

        // ---- batch-8 prefetched remainder loop, slots [RC, lcm) ----
        const unsigned int* cbp = candT + setbase + tid;
        for (int base = RC; base < lcm; base += 8) {
            unsigned int pk[4][8];
            bool act[4];
#pragma unroll
            for (int i = 0; i < 4; i++) {
                act[i] = base < cmc[i];
                const unsigned int* sp = cbp + (size_t)base * N + i * 1024;
#pragma unroll
                for (int b = 0; b < 8; b++)
                    pk[i][b] = act[i] ? sp[(size_t)b * N] : SENTINEL;
            }
#pragma unroll
            for (int i = 0; i < 4; i++) {
                if (act[i]) {
#pragma unroll
                    for (int b = 0; b < 8; b++) {
                        unsigned int v = pk[i][b];
                        float h = (float)__builtin_bit_cast(_Float16, (unsigned short)(v & 0xffffu));
                        int j = v >> 16;
                        float u = fmaf(h, TWO_K, pinK[j] - oK[j]);
                        mt[i] = fmaxf(mt[i], u);
                        s[i] += exp2f(u - mfc[i]);
                    }
                }
            }
        }

        // ---- heavy rows (cnt > MAINCAP): wave-cooperative remainder ----
#pragma unroll
        for (int i = 0; i < 4; i++) {
            unsigned long long hm = __ballot(hvy[i]);
            while (hm) {
                int l = __ffsll((unsigned long long)hm) - 1;
                hm &= hm - 1;
                int row = (tid & ~63) + l + 1024 * i;
                int rcnt = __shfl(ccR[i], l);
                float rmf = __shfl(mfc[i], l);
                const unsigned int* cb2 = candT + setbase + row;
                float sp_ = 0.f, mp_ = -INFINITY;
                for (int t2 = MAINCAP + lane; t2 < rcnt; t2 += 64) {
                    unsigned int v = cb2[(size_t)t2 * N];
                    float h = (float)__builtin_bit_cast(_Float16, (unsigned short)(v & 0xffffu));
                    int j = v >> 16;
                    float u = fmaf(h, TWO_K, pinK[j] - oK[j]);
                    mp_ = fmaxf(mp_, u);
                    sp_ += exp2f(u - rmf);
                }
                for (int off = 32; off > 0; off >>= 1) {
                    sp_ += __shfl_xor(sp_, off);
                    mp_ = fmaxf(mp_, __shfl_xor(mp_, off));
                }
                if (lane == l) { s[i] += sp_; mt[i] = fmaxf(mt[i], mp_); }
            }
        }

        // ---- outputs for sparse rows ----
#pragma unroll
        for (int i = 0; i < 4; i++) {
            if (!dns[i]) {
                int row = tid + 1024 * i;
                poutK[row] = xkc[i] - mfc[i] - __log2f(s[i]) + 12.0f;
                if (odd) lastm0[i] = mt[i]; else lastm1[i] = mt[i];
            }
        }

        // ---- dense fallback rows (wave-cooperative, rare/never) ----
        {
            const _Float16* Mc = odd ? MO : ME;
#pragma unroll
            for (int i = 0; i < 4; i++) {
                unsigned long long dm = __ballot(dns[i]);
                while (dm) {
                    int l = __ffsll((unsigned long long)dm) - 1;
                    dm &= dm - 1;
                    int row = (tid & ~63) + l + 1024 * i;
                    const halfx8* rowp = (const halfx8*)(Mc + (size_t)row * N);
                    float m = -INFINITY, sd = 0.f;
                    for (int ch = lane; ch < N / 8; ch += 64) {
                        halfx8 sv = rowp[ch];
                        int j0 = ch * 8;
                        float u[8];
#pragma unroll
                        for (int k = 0; k < 8; k++)
                            u[k] = fmaf((float)sv[k], TWO_K, pinK[j0 + k] - oK[j0 + k]);
                        float mloc = fmaxf(fmaxf(fmaxf(u[0], u[1]), fmaxf(u[2], u[3])),
                                           fmaxf(fmaxf(u[4], u[5]), fmaxf(u[6], u[7])));
                        float M2 = fmaxf(m, mloc);
                        float acc = 0.f;
#pragma unroll
                        for (int k = 0; k < 8; k++) acc += exp2f(u[k] - M2);
                        sd = sd * exp2f(m - M2) + acc;
                        m = M2;
                    }
                    for (int off = 32; off > 0; off >>= 1) {
                        float m2 = __shfl_xor(m, off), s2 = __shfl_xor(sd, off);
                        float Mx = fmaxf(m, m2);
                        float a1 = (m  == -INFINITY) ? 0.f : sd * exp2f(m  - Mx);
                        float a2 = (m2 == -INFINITY) ? 0.f : s2 * exp2f(m2 - Mx);
                        m = Mx; sd = a1 + a2;
                    }
                    if (lane == l) {
                        poutK[row] = xkc[i] - m - __log2f(sd) + 12.0f;
                        if (odd) lastm0[i] = m; else lastm1[i] = m;
                    }
                }
            }
        }
        __syncthreads();   // poutK complete before next pass reads it
    }

    // write back (rescale to real units): even buffer always; odd buffer for
    // the final phase (finalize needs both). prevmax refreshed for re-BUILD.
    {
        floatx4 v = *(const floatx4*)(PKev + tid * 4);
#pragma unroll
        for (int k = 0; k < 4; k++) v[k] *= INV_K;
        ((floatx4*)gPev)[tid] = v;
    }
    if (write_odd) {
        floatx4 v = *(const floatx4*)(PKod + tid * 4);
#pragma unroll
        for (int k = 0; k < 4; k++) v[k] *= INV_K;
        ((floatx4*)gPod)[tid] = v;
    }
#pragma unroll
    for (int i = 0; i < 4; i++) {
        int r = tid + 1024 * i;
        prevmax[set0 * N + r] = lastm0[i];
        prevmax[set1 * N + r] = lastm1[i];
    }
}

// ---------- final: relu( mean(f_xy+g_xy) - 0.5*mean(f_xx+g_xx) - 0.5*mean(f_yy+g_yy) )
__global__ void finalize_kernel(const float* __restrict__ fxy, const float* __restrict__ gxy,
                                const float* __restrict__ fxx, const float* __restrict__ gxx,
                                const float* __restrict__ fyy, const float* __restrict__ gyy,
                                float* __restrict__ out) {
    __shared__ float sb[256];
    float s = 0.f;
    for (int t = threadIdx.x; t < N; t += 256)
        s += (fxy[t] + gxy[t]) - 0.5f * (fxx[t] + gxx[t]) - 0.5f * (fyy[t] + gyy[t]);
    sb[threadIdx.x] = s;
    __syncthreads();
    for (int off = 128; off > 0; off >>= 1) {
        if (threadIdx.x < off) sb[threadIdx.x] += sb[threadIdx.x + off];
        __syncthreads();
    }
    if (threadIdx.x == 0) {
        float v = sb[0] * (1.0f / 4096.0f);
        out[0] = v > 0.f ? v : 0.f;
    }
}

extern "C" void kernel_launch(void* const* d_in, const int* in_sizes, int n_in,
                              void* d_out, int out_size, void* d_ws, size_t ws_size,
                              hipStream_t stream) {
    const float* x = (const float*)d_in[0];
    const float* y = (const float*)d_in[1];

    const size_t SZ_S = (size_t)N * N * sizeof(_Float16);   // 32 MiB
    const size_t SZ_B = (size_t)N * D * sizeof(__bf16);     // 4 MiB
    const size_t SZ_CAND = (size_t)6 * N * CAP * sizeof(unsigned int);  // 48 MiB

    char* w = (char*)d_ws;
    _Float16* Sxy  = (_Float16*)w; w += SZ_S;
    _Float16* STxy = (_Float16*)w; w += SZ_S;
    _Float16* Sxx  = (_Float16*)w; w += SZ_S;
    _Float16* Syy  = (_Float16*)w; w += SZ_S;
    __bf16* xb = (__bf16*)w;       w += SZ_B;
    __bf16* yb = (__bf16*)w;       w += SZ_B;
    unsigned int* cand = (unsigned int*)w; w += SZ_CAND;
    int* cnt = (int*)w;            w += (size_t)6 * N * sizeof(int);
    float* prevmax = (float*)w;    w += (size_t)6 * N * sizeof(float);
    float* x2 = (float*)w;         w += N * sizeof(float);
    float* y2 = (float*)w;         w += N * sizeof(float);
    float* P[6];
    for (int i = 0; i < 6; i++) { P[i] = (float*)w; w += N * sizeof(float); }

    const size_t need = (size_t)(w - (char*)d_ws);
    const bool sparse_ok = (ws_size >= need);

    cvt_bf16_kernel<<<(N * D + 255) / 256, 256, 0, stream>>>(x, xb, N * D);
    cvt_bf16_kernel<<<(N * D + 255) / 256, 256, 0, stream>>>(y, yb, N * D);
    sqnorm_kernel<<<N, 64, 0, stream>>>(x, x2);
    sqnorm_kernel<<<N, 64, 0, stream>>>(y, y2);

    gemm128_kernel<<<dim3(32, 32), 256, 0, stream>>>(xb, yb, Sxy, STxy, 0);
    gemm128_kernel<<<dim3(32, 32), 256, 0, stream>>>(xb, xb, Sxx, Sxx, 1);
    gemm128_kernel<<<dim3(32, 32), 256, 0, stream>>>(yb, yb, Syy, Syy, 1);

    hipMemsetAsync(P[0], 0, N * sizeof(float), stream);  // g0_xy
    hipMemsetAsync(P[2], 0, N * sizeof(float), stream);  // g0_xx
    hipMemsetAsync(P[4], 0, N * sizeof(float), stream);  // g0_yy

    if (!sparse_ok) {
        // workspace too small for candidate machinery: pure dense loop
        for (int p = 1; p <= SINK_PASSES; p++) {
            lse_full3_kernel<0><<<3 * (N / 4), 256, 0, stream>>>(
                Sxy, STxy, Sxx, Syy, x2, y2,
                P[0], P[1], P[2], P[3], P[4], P[5], p & 1, cand, cnt, prevmax);
        }
    } else {
        // dense warmup 1..8, candidate BUILD at 9,10
        for (int p = 1; p <= 10; p++) {
            int odd = p & 1;
            if (p >= 9)
                lse_full3_kernel<1><<<3 * (N / 4), 256, 0, stream>>>(
                    Sxy, STxy, Sxx, Syy, x2, y2,
                    P[0], P[1], P[2], P[3], P[4], P[5], odd, cand, cnt, prevmax);
            else
                lse_full3_kernel<0><<<3 * (N / 4), 256, 0, stream>>>(
                    Sxy, STxy, Sxx, Syy, x2, y2,
                    P[0], P[1], P[2], P[3], P[4], P[5], odd, cand, cnt, prevmax);
        }

        // sparse passes 11..48: one plain 3-block persistent launch (LDS-only)
        sink_sparse3_kernel<<<3, 1024, 0, stream>>>(
            Sxy, STxy, Sxx, Syy, x2, y2,
            P[0], P[1], P[2], P[3], P[4], P[5],
            cand, cnt, prevmax, 11, 48, 0);

        // candidate re-BUILD at 49,50 (covers drift since build #1)
        for (int p = 49; p <= 50; p++) {
            lse_full3_kernel<1><<<3 * (N / 4), 256, 0, stream>>>(
                Sxy, STxy, Sxx, Syy, x2, y2,
                P[0], P[1], P[2], P[3], P[4], P[5], p & 1, cand, cnt, prevmax);
        }

        // sparse passes 51..100 (finalize needs both parities -> write_odd=1)
        sink_sparse3_kernel<<<3, 1024, 0, stream>>>(
            Sxy, STxy, Sxx, Syy, x2, y2,
            P[0], P[1], P[2], P[3], P[4], P[5],
            cand, cnt, prevmax, 51, 100, 1);
    }
    finalize_kernel<<<1, 256, 0, stream>>>(P[1], P[0], P[3], P[2], P[5], P[4],
                                           (float*)d_out);
}

// Round 6
// 1705.566 us; speedup vs baseline: 1.3707x; 1.3707x over previous
//
#include <hip/hip_runtime.h>
#include <hip/hip_bf16.h>
#include <math.h>

// Problem constants (fixed by reference: x,y are (4096, 512) fp32)
#define N 4096
#define D 512
#define SINK_PASSES 100           // 50 iterations x (f-update, g-update)

// log-domain constants (base-2 internally; v_exp_f32/v_log_f32 are base-2)
#define K_LOG2 14.426950408889634f          // (1/eps) * log2(e), eps = 0.1
#define INV_K  0.06931471805599453f         // 1/K_LOG2 = eps*ln2
#define TWO_K  28.853900817779268f          // 2 * K_LOG2
#define NEG_EPS_LN2 (-0.06931471805599453f) // -eps * ln(2)
#define EPS_NEG_LOGMU 0.8317766166719343f   // -eps * log_mu = eps * log(4096)

// Sparse-candidate machinery: entries with u < rowmax - MARGIN (log2 units)
// contribute < 2^-(MARGIN - drift) each; drift measured ~60 log2 units.
#define CAP 512
#define MARGIN 200.0f
// Sentinel candidate word: j=0, S=-inf (fp16 0xFC00) -> u=-inf -> contributes 0.
#define SENTINEL 0x0000FC00u
// Owner-lane cap: rows with cnt <= MAINCAP are handled by their owner lane;
// rows with cnt > MAINCAP (incl. dense cnt > CAP) go to the parallel queue.
#define MAINCAP 64

typedef __bf16   bf16x8 __attribute__((ext_vector_type(8)));
typedef _Float16 halfx8 __attribute__((ext_vector_type(8)));
typedef float    floatx4 __attribute__((ext_vector_type(4)));
typedef unsigned short ushortx8v __attribute__((ext_vector_type(8)));

// ---------- convert fp32 -> bf16 (GEMM inputs) ----------
__global__ void cvt_bf16_kernel(const float* __restrict__ in, __bf16* __restrict__ out, int count) {
    int idx = blockIdx.x * blockDim.x + threadIdx.x;
    if (idx < count) out[idx] = (__bf16)in[idx];
}

// ---------- row squared norms (fp32 inputs, exact) ----------
__global__ void sqnorm_kernel(const float* __restrict__ in, float* __restrict__ out) {
    int row = blockIdx.x;
    const float* p = in + (size_t)row * D;
    float s = 0.f;
    for (int k = threadIdx.x; k < D; k += 64) { float v = p[k]; s += v * v; }
    for (int off = 32; off > 0; off >>= 1) s += __shfl_down(s, off);
    if (threadIdx.x == 0) out[row] = s;
}

// ---------- 128x128-tile GEMM: out = A @ B^T (fp16), writes tile + transposed tile ----------
__global__ __launch_bounds__(256) void gemm128_kernel(
    const __bf16* __restrict__ A, const __bf16* __restrict__ Bm,
    _Float16* __restrict__ out1, _Float16* __restrict__ out2, int sym) {
    if (sym && blockIdx.x > blockIdx.y) return;
    __shared__ char smem[34816];
    __bf16* ldsA = (__bf16*)smem;           // [128][64] swizzled
    __bf16* ldsB = ldsA + 128 * 64;

    int t = threadIdx.x;
    int w = t >> 6, lane = t & 63;
    int m = lane & 15, q = lane >> 4;
    int wr = w & 1, wc = w >> 1;
    int m0 = blockIdx.x * 128, n0 = blockIdx.y * 128;

    int srow = t >> 1, shalf = t & 1;
    const bf16x8* gA = (const bf16x8*)(A  + (size_t)(m0 + srow) * D + shalf * 32);
    const bf16x8* gB = (const bf16x8*)(Bm + (size_t)(n0 + srow) * D + shalf * 32);

    floatx4 acc[4][4];
#pragma unroll
    for (int i = 0; i < 4; i++)
#pragma unroll
        for (int j = 0; j < 4; j++) acc[i][j] = (floatx4){0.f, 0.f, 0.f, 0.f};

    for (int slab = 0; slab < 8; slab++) {
        bf16x8 va[4], vb[4];
#pragma unroll
        for (int i = 0; i < 4; i++) {
            va[i] = gA[slab * 8 + i];
            vb[i] = gB[slab * 8 + i];
        }
        __syncthreads();
#pragma unroll
        for (int i = 0; i < 4; i++) {
            int cp = (shalf * 4 + i) ^ (srow & 7);
            *(bf16x8*)(ldsA + srow * 64 + cp * 8) = va[i];
            *(bf16x8*)(ldsB + srow * 64 + cp * 8) = vb[i];
        }
        __syncthreads();
#pragma unroll
        for (int kk = 0; kk < 2; kk++) {
            bf16x8 af[4], bfr[4];
#pragma unroll
            for (int mt = 0; mt < 4; mt++) {
                int cp = (kk * 4 + q) ^ (m & 7);
                af[mt]  = *(const bf16x8*)(ldsA + (wr * 64 + mt * 16 + m) * 64 + cp * 8);
                bfr[mt] = *(const bf16x8*)(ldsB + (wc * 64 + mt * 16 + m) * 64 + cp * 8);
            }
#pragma unroll
            for (int mt = 0; mt < 4; mt++)
#pragma unroll
                for (int nt = 0; nt < 4; nt++)
                    acc[mt][nt] = __builtin_amdgcn_mfma_f32_16x16x32_bf16(
                        af[mt], bfr[nt], acc[mt][nt], 0, 0, 0);
        }
    }

    __syncthreads();
    _Float16* et = (_Float16*)smem + w * (64 * 66);
#pragma unroll
    for (int mt = 0; mt < 4; mt++)
#pragma unroll
        for (int nt = 0; nt < 4; nt++)
#pragma unroll
            for (int r = 0; r < 4; r++)
                et[(mt * 16 + q * 4 + r) * 66 + nt * 16 + m] = (_Float16)acc[mt][nt][r];

    int l3 = lane >> 3, c8 = lane & 7;
#pragma unroll
    for (int rr = 0; rr < 8; rr++) {
        int rl = rr * 8 + l3;
        halfx8 v = *(const halfx8*)(et + rl * 66 + c8 * 8);
        *(halfx8*)(out1 + (size_t)(m0 + wr * 64 + rl) * N + n0 + wc * 64 + c8 * 8) = v;
    }
#pragma unroll
    for (int rr = 0; rr < 8; rr++) {
        int rT = rr * 8 + l3;
        halfx8 v;
#pragma unroll
        for (int k = 0; k < 8; k++) v[k] = et[(c8 * 8 + k) * 66 + rT];
        *(halfx8*)(out2 + (size_t)(n0 + wc * 64 + rT) * N + m0 + wr * 64 + c8 * 8) = v;
    }
}

// ---------- full Sinkhorn pass (3 pairs, 1 row/wave, 3072 blocks) ----------
// BUILD=1: collect candidates u >= prevmax - MARGIN via ballot compaction into
// the TRANSPOSED layout candT[set][slot][row] (addr = (set*CAP+slot)*N + row),
// then SENTINEL-pad each list to a multiple of 8.
template<int BUILD>
__global__ __launch_bounds__(256) void lse_full3_kernel(
    const _Float16* __restrict__ Sxy, const _Float16* __restrict__ STxy,
    const _Float16* __restrict__ Sxx, const _Float16* __restrict__ Syy,
    const float* __restrict__ x2, const float* __restrict__ y2,
    float* __restrict__ Pxy0, float* __restrict__ Pxy1,
    float* __restrict__ Pxx0, float* __restrict__ Pxx1,
    float* __restrict__ Pyy0, float* __restrict__ Pyy1,
    int odd,
    unsigned int* __restrict__ cand, int* __restrict__ cnt,
    float* __restrict__ prevmax) {
    __shared__ float gykT[8 * 512];
    int pair = blockIdx.x >> 10;
    int blk = blockIdx.x & 1023;
    const _Float16* M;
    const float *own, *other, *pin;
    float* pout;
    if (pair == 0) {
        if (odd) { M = Sxy;  own = x2; other = y2; pin = Pxy0; pout = Pxy1; }
        else     { M = STxy; own = y2; other = x2; pin = Pxy1; pout = Pxy0; }
    } else if (pair == 1) {
        M = Sxx; own = x2; other = x2;
        if (odd) { pin = Pxx0; pout = Pxx1; } else { pin = Pxx1; pout = Pxx0; }
    } else {
        M = Syy; own = y2; other = y2;
        if (odd) { pin = Pyy0; pout = Pyy1; } else { pin = Pyy1; pout = Pyy0; }
    }

    int wave = threadIdx.x >> 6, lane = threadIdx.x & 63;

    {   // stage gykT[(j&7)*512 + (j>>3)] = (pin[j] - other[j]) * K
        const floatx4* pi4 = (const floatx4*)pin;
        const floatx4* so4 = (const floatx4*)other;
        for (int tt = threadIdx.x; tt < N / 4; tt += 256) {
            floatx4 p = pi4[tt], o = so4[tt];
            int j = tt * 4;
#pragma unroll
            for (int k2 = 0; k2 < 4; k2++) {
                int jj = j + k2;
                gykT[(jj & 7) * 512 + (jj >> 3)] = (p[k2] - o[k2]) * K_LOG2;
            }
        }
    }
    __syncthreads();

    int row = blk * 4 + wave;
    int set = pair * 2 + (odd ? 0 : 1);
    int idx = set * N + row;
    float thr = 0.f;
    size_t cbase = 0;
    int ncand = 0;
    unsigned long long lt_mask = (1ull << lane) - 1ull;
    if (BUILD) { thr = prevmax[idx] - MARGIN; cbase = (size_t)set * CAP * N + row; }

    const halfx8* srow = (const halfx8*)(M + (size_t)row * N);
    float m = -INFINITY, s = 0.f;
#pragma unroll
    for (int c = 0; c < 8; c++) {
        int chunk = c * 64 + lane;
        halfx8 sv = srow[chunk];
        int j0 = chunk * 8;
        float u[8];
#pragma unroll
        for (int k = 0; k < 8; k++)
            u[k] = fmaf((float)sv[k], TWO_K, gykT[k * 512 + chunk]);
        float mloc = fmaxf(fmaxf(fmaxf(u[0], u[1]), fmaxf(u[2], u[3])),
                           fmaxf(fmaxf(u[4], u[5]), fmaxf(u[6], u[7])));
        if (BUILD) {
            if (__ballot(mloc >= thr)) {
                ushortx8v sb = __builtin_bit_cast(ushortx8v, sv);
#pragma unroll
                for (int k = 0; k < 8; k++) {
                    bool hit = (u[k] >= thr);
                    unsigned long long mask = __ballot(hit);
                    if (hit) {
                        int slot = ncand + __popcll(mask & lt_mask);
                        if (slot < CAP)
                            cand[cbase + (size_t)slot * N] = ((unsigned int)(j0 + k) << 16) | (unsigned int)sb[k];
                    }
                    ncand += (int)__popcll(mask);
                }
            }
        }
        float M2 = fmaxf(m, mloc);
        float acc = 0.f;
#pragma unroll
        for (int k = 0; k < 8; k++) acc += exp2f(u[k] - M2);
        s = s * exp2f(m - M2) + acc;
        m = M2;
    }
    if (BUILD) {
        // sentinel-pad to a multiple of 8 (ncand is identical on all lanes)
        int padded = (ncand + 7) & ~7;
        if (padded > CAP) padded = CAP;
        for (int sl = ncand + lane; sl < padded; sl += 64)
            cand[cbase + (size_t)sl * N] = SENTINEL;
    }
    for (int off = 32; off > 0; off >>= 1) {
        float m2 = __shfl_down(m, off), s2 = __shfl_down(s, off);
        float Mx = fmaxf(m, m2);
        s = s * exp2f(m - Mx) + s2 * exp2f(m2 - Mx);
        m = Mx;
    }
    if (lane == 0) {
        float xk = own[row] * K_LOG2;
        pout[row] = NEG_EPS_LN2 * (m + __log2f(s) - xk) + EPS_NEG_LOGMU;
        prevmax[idx] = m;
        if (BUILD) cnt[idx] = ncand;
    }
}

// ---------- persistent sparse phase: ONE block per pair, all state in LDS ----------
// 3 blocks x 1024 threads, plain launch. Per pass:
//   [build Q[j] = pinK[j] - othK[j] in LDS]  B1
//   [owner lanes: rows with cnt<=MAINCAP, batch-8 sentinel loop, 1 LDS gather
//    per candidate (Q)]  [parallel queue: rows with cnt>MAINCAP (incl. dense
//    cnt>CAP) processed wave-cooperatively, waves grab rows round-robin]  B2
// Queue rows use the (per-pass-refreshed) prevmax as defer-max normalizer and
// write poutK + prevmax directly. Owner rows keep fixed build-time normalizer
// and write prevmax once at the end. No per-thread arrays beyond 8-reg batch
// (R5 lesson: 1024-thr blocks cap VGPRs; launch_bounds(1024,4) allows 128).
__global__ __launch_bounds__(1024, 4) void sink_sparse3_kernel(
    const _Float16* __restrict__ Sxy, const _Float16* __restrict__ STxy,
    const _Float16* __restrict__ Sxx, const _Float16* __restrict__ Syy,
    const float* __restrict__ x2, const float* __restrict__ y2,
    float* __restrict__ Pxy0, float* __restrict__ Pxy1,
    float* __restrict__ Pxx0, float* __restrict__ Pxx1,
    float* __restrict__ Pyy0, float* __restrict__ Pyy1,
    const unsigned int* __restrict__ candT, const int* __restrict__ cnt,
    float* __restrict__ prevmax, int p_start, int p_end, int write_odd) {
    __shared__ float PKev[N];    // even-set potentials * K (read by odd passes)
    __shared__ float PKod[N];    // odd-set potentials * K
    __shared__ float othKO[N];   // other*K for odd passes
    __shared__ float othKE[N];   // other*K for even passes
    __shared__ float Qt[N];      // per-pass Q[j] = pinK[j] - othK[j]
    __shared__ unsigned qarr[2][N];  // queue: row | (cnt<<16), per parity
    __shared__ int qn[2];

    int pair = blockIdx.x;
    int tid = threadIdx.x;
    int lane = tid & 63;
    int wave = tid >> 6;

    const _Float16 *MO, *ME;            // dense-fallback matrices, odd/even
    const float *ownO, *ownE, *othO, *othE;
    float *gPev, *gPod;                 // global ping-pong buffers
    if (pair == 0) {
        MO = Sxy;  ME = STxy; ownO = x2; othO = y2; ownE = y2; othE = x2;
        gPev = Pxy0; gPod = Pxy1;
    } else if (pair == 1) {
        MO = Sxx; ME = Sxx; ownO = x2; othO = x2; ownE = x2; othE = x2;
        gPev = Pxx0; gPod = Pxx1;
    } else {
        MO = Syy; ME = Syy; ownO = y2; othO = y2; ownE = y2; othE = y2;
        gPev = Pyy0; gPod = Pyy1;
    }
    int set0 = pair * 2;        // odd passes
    int set1 = pair * 2 + 1;    // even passes

    if (tid < 2) qn[tid] = 0;

    {   // init LDS: scaled even-buffer + fixed othK tables (vec4 per thread)
        floatx4 g = ((const floatx4*)gPev)[tid];
        floatx4 oo = ((const floatx4*)othO)[tid];
        floatx4 oe = ((const floatx4*)othE)[tid];
        floatx4 gs, os, es;
#pragma unroll
        for (int k = 0; k < 4; k++) {
            gs[k] = g[k] * K_LOG2;
            os[k] = oo[k] * K_LOG2;
            es[k] = oe[k] * K_LOG2;
        }
        *(floatx4*)(PKev + tid * 4) = gs;
        *(floatx4*)(othKO + tid * 4) = os;
        *(floatx4*)(othKE + tid * 4) = es;
    }

    // per-lane per-row state (4 rows, 2 parities)
    int   c0[4], c1[4];                  // raw counts
    int   cm0[4], cm1[4];                // owner batch bounds (<= MAINCAP)
    float mf0[4], mf1[4], xk0[4], xk1[4];
    float lastm0[4], lastm1[4];
    bool  mine0[4], mine1[4];
#pragma unroll
    for (int i = 0; i < 4; i++) {
        int r = tid + 1024 * i;
        int cc0 = cnt[set0 * N + r], cc1 = cnt[set1 * N + r];
        c0[i] = cc0; c1[i] = cc1;
        mine0[i] = (cc0 >= 1 && cc0 <= MAINCAP);
        mine1[i] = (cc1 >= 1 && cc1 <= MAINCAP);
        cm0[i] = mine0[i] ? ((cc0 + 7) & ~7) : 0;
        cm1[i] = mine1[i] ? ((cc1 + 7) & ~7) : 0;
        mf0[i] = prevmax[set0 * N + r];
        mf1[i] = prevmax[set1 * N + r];
        lastm0[i] = mf0[i]; lastm1[i] = mf1[i];
        xk0[i] = ownO[r] * K_LOG2;
        xk1[i] = ownE[r] * K_LOG2;
    }
    // wave-uniform owner batch bounds per parity
    int lcm0 = 0, lcm1 = 0;
#pragma unroll
    for (int i = 0; i < 4; i++) {
        lcm0 = cm0[i] > lcm0 ? cm0[i] : lcm0;
        lcm1 = cm1[i] > lcm1 ? cm1[i] : lcm1;
    }
    for (int off = 32; off > 0; off >>= 1) {
        int a = __shfl_xor(lcm0, off); lcm0 = a > lcm0 ? a : lcm0;
        int b = __shfl_xor(lcm1, off); lcm1 = b > lcm1 ? b : lcm1;
    }
    __syncthreads();   // LDS init + qn zero complete

    // enqueue heavy/dense rows (cnt > MAINCAP); visibility via first B1
#pragma unroll
    for (int i = 0; i < 4; i++) {
        int r = tid + 1024 * i;
        if (c0[i] > MAINCAP) {
            int sl = atomicAdd(&qn[0], 1);
            qarr[0][sl] = (unsigned)r | ((unsigned)c0[i] << 16);
        }
        if (c1[i] > MAINCAP) {
            int sl = atomicAdd(&qn[1], 1);
            qarr[1][sl] = (unsigned)r | ((unsigned)c1[i] << 16);
        }
    }

    for (int p = p_start; p <= p_end; ++p) {
        int odd = p & 1;
        float* pinK  = odd ? PKev : PKod;
        float* poutK = odd ? PKod : PKev;

        // ---- build Q = pinK - othK (streaming, conflict-free) ----
        {
            floatx4 pv = *(const floatx4*)(pinK + tid * 4);
            floatx4 ov = *(const floatx4*)((odd ? othKO : othKE) + tid * 4);
            floatx4 q;
#pragma unroll
            for (int k = 0; k < 4; k++) q[k] = pv[k] - ov[k];
            *(floatx4*)(Qt + tid * 4) = q;
        }
        __syncthreads();   // B1: Q ready (also orders queue init on 1st pass)

        // per-parity owner state (constant-indexed selects -> stays in regs)
        int cmc[4]; float mfc[4], xkc[4]; bool mn[4];
#pragma unroll
        for (int i = 0; i < 4; i++) {
            cmc[i] = odd ? cm0[i] : cm1[i];
            mfc[i] = odd ? mf0[i] : mf1[i];
            xkc[i] = odd ? xk0[i] : xk1[i];
            mn[i]  = odd ? mine0[i] : mine1[i];
        }
        int lcm = odd ? lcm0 : lcm1;
        int setc = odd ? set0 : set1;
        size_t setbase = (size_t)setc * CAP * N;

        // ---- owner batch-8 loop, slots [0, lcm), 1 LDS gather/candidate ----
        float s[4] = {0.f, 0.f, 0.f, 0.f};
        float mt[4] = {-INFINITY, -INFINITY, -INFINITY, -INFINITY};
        const unsigned int* cbp = candT + setbase + tid;
        for (int base = 0; base < lcm; base += 8) {
            unsigned int pk[4][8];
#pragma unroll
            for (int i = 0; i < 4; i++) {
                bool act = base < cmc[i];
                const unsigned int* sp = cbp + (size_t)base * N + i * 1024;
#pragma unroll
                for (int b = 0; b < 8; b++)
                    pk[i][b] = act ? sp[(size_t)b * N] : SENTINEL;
            }
#pragma unroll
            for (int i = 0; i < 4; i++) {
                if (base < cmc[i]) {
#pragma unroll
                    for (int b = 0; b < 8; b++) {
                        unsigned int v = pk[i][b];
                        float h = (float)__builtin_bit_cast(_Float16, (unsigned short)(v & 0xffffu));
                        int j = v >> 16;
                        float u = fmaf(h, TWO_K, Qt[j]);
                        mt[i] = fmaxf(mt[i], u);
                        s[i] += exp2f(u - mfc[i]);
                    }
                }
            }
        }
        // owner outputs
#pragma unroll
        for (int i = 0; i < 4; i++) {
            if (mn[i]) {
                int row = tid + 1024 * i;
                poutK[row] = xkc[i] - mfc[i] - __log2f(s[i]) + 12.0f;
                if (odd) lastm0[i] = mt[i]; else lastm1[i] = mt[i];
            }
        }

        // ---- parallel queue: heavy (cnt>MAINCAP) and dense (cnt>CAP) rows ----
        {
            int np = qn[odd ? 0 : 1];
            if (np) {
                const _Float16* Mc = odd ? MO : ME;
                const float* xkT = odd ? othKE : othKO;   // own*K table (see text)
                for (int qi = wave; qi < np; qi += 16) {
                    unsigned e = qarr[odd ? 0 : 1][qi];
                    int row = (int)(e & 0xffffu);
                    int rc  = (int)(e >> 16);
                    int idx = setc * N + row;
                    float pm = prevmax[idx];   // refreshed normalizer (defer-max)
                    float m = -INFINITY, ss = 0.f;
                    if (rc <= CAP) {
                        const unsigned int* cb2 = candT + setbase + row;
                        for (int t = lane; t < rc; t += 64) {
                            unsigned int v = cb2[(size_t)t * N];
                            float h = (float)__builtin_bit_cast(_Float16, (unsigned short)(v & 0xffffu));
                            int j = v >> 16;
                            float u = fmaf(h, TWO_K, Qt[j]);
                            m = fmaxf(m, u);
                            ss += exp2f(u - pm);
                        }
                    } else {
                        const halfx8* rowp = (const halfx8*)(Mc + (size_t)row * N);
                        for (int ch = lane; ch < N / 8; ch += 64) {
                            halfx8 sv = rowp[ch];
                            int j0 = ch * 8;
#pragma unroll
                            for (int k = 0; k < 8; k++) {
                                float u = fmaf((float)sv[k], TWO_K, Qt[j0 + k]);
                                m = fmaxf(m, u);
                                ss += exp2f(u - pm);
                            }
                        }
                    }
                    for (int off = 32; off > 0; off >>= 1) {
                        ss += __shfl_xor(ss, off);
                        m = fmaxf(m, __shfl_xor(m, off));
                    }
                    if (lane == 0) {
                        poutK[row] = xkT[row] - pm - __log2f(ss) + 12.0f;
                        prevmax[idx] = m;
                    }
                }
            }
        }
        __syncthreads();   // B2: poutK complete before next pass builds Q
    }

    // write back (rescale to real units): even buffer always; odd buffer for
    // the final phase (finalize needs both). prevmax refreshed for re-BUILD
    // (owner rows only; queue rows already wrote theirs every pass).
    {
        floatx4 v = *(const floatx4*)(PKev + tid * 4);
#pragma unroll
        for (int k = 0; k < 4; k++) v[k] *= INV_K;
        ((floatx4*)gPev)[tid] = v;
    }
    if (write_odd) {
        floatx4 v = *(const floatx4*)(PKod + tid * 4);
#pragma unroll
        for (int k = 0; k < 4; k++) v[k] *= INV_K;
        ((floatx4*)gPod)[tid] = v;
    }
#pragma unroll
    for (int i = 0; i < 4; i++) {
        int r = tid + 1024 * i;
        if (mine0[i]) prevmax[set0 * N + r] = lastm0[i];
        if (mine1[i]) prevmax[set1 * N + r] = lastm1[i];
    }
}

// ---------- final: relu( mean(f_xy+g_xy) - 0.5*mean(f_xx+g_xx) - 0.5*mean(f_yy+g_yy) )
__global__ void finalize_kernel(const float* __restrict__ fxy, const float* __restrict__ gxy,
                                const float* __restrict__ fxx, const float* __restrict__ gxx,
                                const float* __restrict__ fyy, const float* __restrict__ gyy,
                                float* __restrict__ out) {
    __shared__ float sb[256];
    float s = 0.f;
    for (int t = threadIdx.x; t < N; t += 256)
        s += (fxy[t] + gxy[t]) - 0.5f * (fxx[t] + gxx[t]) - 0.5f * (fyy[t] + gyy[t]);
    sb[threadIdx.x] = s;
    __syncthreads();
    for (int off = 128; off > 0; off >>= 1) {
        if (threadIdx.x < off) sb[threadIdx.x] += sb[threadIdx.x + off];
        __syncthreads();
    }
    if (threadIdx.x == 0) {
        float v = sb[0] * (1.0f / 4096.0f);
        out[0] = v > 0.f ? v : 0.f;
    }
}

extern "C" void kernel_launch(void* const* d_in, const int* in_sizes, int n_in,
                              void* d_out, int out_size, void* d_ws, size_t ws_size,
                              hipStream_t stream) {
    const float* x = (const float*)d_in[0];
    const float* y = (const float*)d_in[1];

    const size_t SZ_S = (size_t)N * N * sizeof(_Float16);   // 32 MiB
    const size_t SZ_B = (size_t)N * D * sizeof(__bf16);     // 4 MiB
    const size_t SZ_CAND = (size_t)6 * N * CAP * sizeof(unsigned int);  // 48 MiB

    char* w = (char*)d_ws;
    _Float16* Sxy  = (_Float16*)w; w += SZ_S;
    _Float16* STxy = (_Float16*)w; w += SZ_S;
    _Float16* Sxx  = (_Float16*)w; w += SZ_S;
    _Float16* Syy  = (_Float16*)w; w += SZ_S;
    __bf16* xb = (__bf16*)w;       w += SZ_B;
    __bf16* yb = (__bf16*)w;       w += SZ_B;
    unsigned int* cand = (unsigned int*)w; w += SZ_CAND;
    int* cnt = (int*)w;            w += (size_t)6 * N * sizeof(int);
    float* prevmax = (float*)w;    w += (size_t)6 * N * sizeof(float);
    float* x2 = (float*)w;         w += N * sizeof(float);
    float* y2 = (float*)w;         w += N * sizeof(float);
    float* P[6];
    for (int i = 0; i < 6; i++) { P[i] = (float*)w; w += N * sizeof(float); }

    const size_t need = (size_t)(w - (char*)d_ws);
    const bool sparse_ok = (ws_size >= need);

    cvt_bf16_kernel<<<(N * D + 255) / 256, 256, 0, stream>>>(x, xb, N * D);
    cvt_bf16_kernel<<<(N * D + 255) / 256, 256, 0, stream>>>(y, yb, N * D);
    sqnorm_kernel<<<N, 64, 0, stream>>>(x, x2);
    sqnorm_kernel<<<N, 64, 0, stream>>>(y, y2);

    gemm128_kernel<<<dim3(32, 32), 256, 0, stream>>>(xb, yb, Sxy, STxy, 0);
    gemm128_kernel<<<dim3(32, 32), 256, 0, stream>>>(xb, xb, Sxx, Sxx, 1);
    gemm128_kernel<<<dim3(32, 32), 256, 0, stream>>>(yb, yb, Syy, Syy, 1);

    hipMemsetAsync(P[0], 0, N * sizeof(float), stream);  // g0_xy
    hipMemsetAsync(P[2], 0, N * sizeof(float), stream);  // g0_xx
    hipMemsetAsync(P[4], 0, N * sizeof(float), stream);  // g0_yy

    if (!sparse_ok) {
        // workspace too small for candidate machinery: pure dense loop
        for (int p = 1; p <= SINK_PASSES; p++) {
            lse_full3_kernel<0><<<3 * (N / 4), 256, 0, stream>>>(
                Sxy, STxy, Sxx, Syy, x2, y2,
                P[0], P[1], P[2], P[3], P[4], P[5], p & 1, cand, cnt, prevmax);
        }
    } else {
        // dense warmup 1..8, candidate BUILD at 9,10
        for (int p = 1; p <= 10; p++) {
            int odd = p & 1;
            if (p >= 9)
                lse_full3_kernel<1><<<3 * (N / 4), 256, 0, stream>>>(
                    Sxy, STxy, Sxx, Syy, x2, y2,
                    P[0], P[1], P[2], P[3], P[4], P[5], odd, cand, cnt, prevmax);
            else
                lse_full3_kernel<0><<<3 * (N / 4), 256, 0, stream>>>(
                    Sxy, STxy, Sxx, Syy, x2, y2,
                    P[0], P[1], P[2], P[3], P[4], P[5], odd, cand, cnt, prevmax);
        }

        // sparse passes 11..48: one plain 3-block persistent launch (LDS-only)
        sink_sparse3_kernel<<<3, 1024, 0, stream>>>(
            Sxy, STxy, Sxx, Syy, x2, y2,
            P[0], P[1], P[2], P[3], P[4], P[5],
            cand, cnt, prevmax, 11, 48, 0);

        // candidate re-BUILD at 49,50 (covers drift since build #1)
        for (int p = 49; p <= 50; p++) {
            lse_full3_kernel<1><<<3 * (N / 4), 256, 0, stream>>>(
                Sxy, STxy, Sxx, Syy, x2, y2,
                P[0], P[1], P[2], P[3], P[4], P[5], p & 1, cand, cnt, prevmax);
        }

        // sparse passes 51..100 (finalize needs both parities -> write_odd=1)
        sink_sparse3_kernel<<<3, 1024, 0, stream>>>(
            Sxy, STxy, Sxx, Syy, x2, y2,
            P[0], P[1], P[2], P[3], P[4], P[5],
            cand, cnt, prevmax, 51, 100, 1);
    }
    finalize_kernel<<<1, 256, 0, stream>>>(P[1], P[0], P[3], P[2], P[5], P[4],
                                           (float*)d_out);
}